// Round 9
// baseline (1268.101 us; speedup 1.0000x reference)
//
#include <hip/hip_runtime.h>

#define DIM 768
#define TD 2304
#define NB 8
#define NS 4096
#define NE 6

// ws layout (float offsets)
#define OFF_QC3    0            // [2304][20]: per col, 0-5 Q, 6-11 P, 12-17 A1, 18-19 pad
#define OFF_A2F    46080        // [2304][6] delta-mean fold
#define OFF_CB0    59904        // [16]
#define OFF_ACCSUM 59920        // [8][6] + pad = 64
#define OFF_CONSTB 59984        // [8][6] + pad = 64
#define OFF_QP     60048        // [3][32768][12]

// ---------------- kernel B: fold all coefficient matrices (+cb0, +accsum zero) ----
__global__ __launch_bounds__(256) void k_fold(
    const float* __restrict__ Wspat, const float* __restrict__ Wtemp,
    const float* __restrict__ Wsync, const float* __restrict__ Wroute,
    const float* __restrict__ Wglob, const float* __restrict__ bglob,
    const float* __restrict__ broute, const float* __restrict__ bspat,
    const float* __restrict__ btemp, const float* __restrict__ bsync,
    float* __restrict__ Qc3, float* __restrict__ A2F,
    float* __restrict__ cb0, float* __restrict__ accsum)
{
    __shared__ float lwr[288 * NE];
    __shared__ float lgf[224 * NE];
    const int t = threadIdx.x;
    for (int i = t; i < 288 * NE; i += 256) lwr[i] = Wroute[i];
    __syncthreads();
    if (t < 224) {
        float g[NE] = {0, 0, 0, 0, 0, 0};
        for (int o = 0; o < 64; ++o) {
            const float w = Wglob[t * 64 + o];
            #pragma unroll
            for (int e = 0; e < NE; ++e) g[e] += w * lwr[(224 + o) * NE + e];
        }
        #pragma unroll
        for (int e = 0; e < NE; ++e) lgf[t * NE + e] = g[e];
    }
    __syncthreads();
    if (blockIdx.x == 0) {
        if (t < NE) {
            float a = broute[t];
            for (int o = 0; o < 64; ++o)  a += bglob[o] * lwr[(224 + o) * NE + t];
            for (int o = 0; o < 128; ++o) a += bspat[o] * (lwr[o * NE + t] + lgf[o * NE + t]);
            for (int o = 0; o < 64; ++o)  a += btemp[o] * (lwr[(128 + o) * NE + t] + lgf[(128 + o) * NE + t]);
            for (int o = 0; o < 32; ++o)  a += bsync[o] * (lwr[(192 + o) * NE + t] + lgf[(192 + o) * NE + t]);
            cb0[t] = a;
        }
        if (t >= 128 && t < 192) accsum[t - 128] = 0.f;
    }

    const int d = blockIdx.x * 256 + t;          // exactly 2304 threads
    const int st = d / DIM, dd = d - st * DIM;

    float p[NE] = {0, 0, 0, 0, 0, 0}, a2[NE] = {0, 0, 0, 0, 0, 0};
    for (int o = 0; o < 64; ++o) {
        const float w = Wtemp[d * 64 + o];
        #pragma unroll
        for (int e = 0; e < NE; ++e) {
            p[e]  += w * lwr[(128 + o) * NE + e];
            a2[e] += w * lgf[(128 + o) * NE + e];
        }
    }
    float qq[NE], a1[NE];
    #pragma unroll
    for (int e = 0; e < NE; ++e) { qq[e] = p[e]; a1[e] = 0.f; }
    for (int o = 0; o < 128; ++o) {
        const float w = Wspat[d * 128 + o];
        #pragma unroll
        for (int e = 0; e < NE; ++e) {
            qq[e] += w * lwr[o * NE + e];
            a1[e] += w * lgf[o * NE + e];
        }
    }
    if (st != 0) {
        const float sg = (st == 1) ? 1.f : -1.f;
        for (int o = 0; o < 32; ++o) {
            const float w = sg * Wsync[dd * 32 + o];
            #pragma unroll
            for (int e = 0; e < NE; ++e) {
                qq[e] += w * lwr[(192 + o) * NE + e];
                a1[e] += w * lgf[(192 + o) * NE + e];
            }
        }
    }
    #pragma unroll
    for (int e = 0; e < NE; ++e) {
        Qc3[(size_t)d * 20 + e]      = qq[e];
        Qc3[(size_t)d * 20 + 6 + e]  = p[e];
        Qc3[(size_t)d * 20 + 12 + e] = a1[e];
        A2F[d * NE + e] = a2[e];
    }
}

// ---------------- kernel C: main streaming pass ----------------
// grid = 8b * 3st * 64rg = 1536 blocks; 256 thr = 4 waves. Block = 64 rows.
// Lane l = row; wave w owns cols w*16..w*16+15 of each 64-col chunk.
// BOTH x and the per-chunk coefficient slab are staged in LDS, double-
// buffered, 1 barrier/chunk. Inner loop: x via ds_read_b128 (2-way banks,
// free) + coefficients via wave-uniform broadcast LDS reads at immediate
// offsets + 18 FMA/col. No global ops, no cross-lane ops in the loop.
__global__ __launch_bounds__(256, 3) void k_main(
    const float* __restrict__ xt, const float* __restrict__ xa, const float* __restrict__ xv,
    const float* __restrict__ Qc3, float* __restrict__ accsum, float* __restrict__ qp)
{
    __shared__ float smem[2 * 64 * 65];     // x tiles (33.3 KB); reused for end-reduce
    __shared__ float scoef[2 * 64 * 20];    // coef slabs (10.2 KB)
    const int t = threadIdx.x;
    const int l = t & 63;
    const int w = __builtin_amdgcn_readfirstlane(t >> 6);
    const int bid = blockIdx.x;
    const int rg = bid & 63;
    const int st = (bid >> 6) % 3;
    const int bb = bid / 192;

    const float* X = (st == 0) ? xt : ((st == 1) ? xa : xv);
    const int row0 = rg * 64;

    // x staging: thread stages row t>>2, 16 cols at (t&3)*16 (64B/lane, coalesced)
    const int srow = t >> 2, scol = (t & 3) * 16;
    const float* gsrc = X + (size_t)(bb * NS + row0 + srow) * DIM + scol;
    const float* cgsrc = Qc3 + (size_t)st * DIM * 20;    // chunk c slab at + c*1280

    float* rb = smem;            float* wb = smem + 64 * 65;
    float* rc = scoef;           float* wc = scoef + 64 * 20;

    float4 g0, g1, g2, g3, cf0, cf1;
    g0 = *(const float4*)(gsrc + 0);
    g1 = *(const float4*)(gsrc + 4);
    g2 = *(const float4*)(gsrc + 8);
    g3 = *(const float4*)(gsrc + 12);
    cf0 = *(const float4*)(cgsrc + t * 4);                    // 256 float4 = 1024 floats
    if (t < 64) cf1 = *(const float4*)(cgsrc + 1024 + t * 4); // remaining 256 floats
    {
        float* wp = rb + srow * 65 + scol;
        *(float4*)(wp + 0) = g0; *(float4*)(wp + 4)  = g1;
        *(float4*)(wp + 8) = g2; *(float4*)(wp + 12) = g3;
        *(float4*)(rc + t * 4) = cf0;
        if (t < 64) *(float4*)(rc + 1024 + t * 4) = cf1;
    }
    __syncthreads();

    float aq[6] = {0, 0, 0, 0, 0, 0};
    float ap[6] = {0, 0, 0, 0, 0, 0};
    float ag[6] = {0, 0, 0, 0, 0, 0};

    #pragma unroll 1
    for (int c = 0; c < 12; ++c) {
        if (c < 11) {                       // issue next-chunk loads early
            const float* gs = gsrc + (c + 1) * 64;
            g0 = *(const float4*)(gs + 0);
            g1 = *(const float4*)(gs + 4);
            g2 = *(const float4*)(gs + 8);
            g3 = *(const float4*)(gs + 12);
            const float* cs = cgsrc + (size_t)(c + 1) * 1280;
            cf0 = *(const float4*)(cs + t * 4);
            if (t < 64) cf1 = *(const float4*)(cs + 1024 + t * 4);
        }
        const float* xr = rb + l * 65 + w * 16;
        const float* cw = rc + w * 320;     // wave-uniform base; imm offsets below
        #pragma unroll
        for (int j = 0; j < 4; ++j) {
            const float4 xv4 = *(const float4*)(xr + j * 4);
            #pragma unroll
            for (int kk = 0; kk < 4; ++kk) {
                const float xk = (kk == 0) ? xv4.x : (kk == 1) ? xv4.y : (kk == 2) ? xv4.z : xv4.w;
                const float* cc = cw + (j * 4 + kk) * 20;
                const float4 u0 = *(const float4*)(cc + 0);
                const float4 u1 = *(const float4*)(cc + 4);
                const float4 u2 = *(const float4*)(cc + 8);
                const float4 u3 = *(const float4*)(cc + 12);
                const float2 u4 = *(const float2*)(cc + 16);
                aq[0] += xk * u0.x; aq[1] += xk * u0.y; aq[2] += xk * u0.z; aq[3] += xk * u0.w;
                aq[4] += xk * u1.x; aq[5] += xk * u1.y;
                ap[0] += xk * u1.z; ap[1] += xk * u1.w;
                ap[2] += xk * u2.x; ap[3] += xk * u2.y; ap[4] += xk * u2.z; ap[5] += xk * u2.w;
                ag[0] += xk * u3.x; ag[1] += xk * u3.y; ag[2] += xk * u3.z; ag[3] += xk * u3.w;
                ag[4] += xk * u4.x; ag[5] += xk * u4.y;
            }
        }
        if (c < 11) {
            float* wp = wb + srow * 65 + scol;
            *(float4*)(wp + 0) = g0; *(float4*)(wp + 4)  = g1;
            *(float4*)(wp + 8) = g2; *(float4*)(wp + 12) = g3;
            *(float4*)(wc + t * 4) = cf0;
            if (t < 64) *(float4*)(wc + 1024 + t * 4) = cf1;
        }
        __syncthreads();
        float* tp = rb; rb = wb; wb = tp;
        tp = rc; rc = wc; wc = tp;
    }

    // end-reduce across the 4 waves (once per kernel), reusing smem
    float* red = smem;
    {
        float* rp = red + (l * 4 + w) * 20;
        #pragma unroll
        for (int e = 0; e < 6; ++e) { rp[e] = aq[e]; rp[6 + e] = ap[e]; rp[12 + e] = ag[e]; }
    }
    __syncthreads();
    if (t < 64) {
        const float* r0 = red + (t * 4 + 0) * 20;
        const float* r1 = red + (t * 4 + 1) * 20;
        const float* r2 = red + (t * 4 + 2) * 20;
        const float* r3 = red + (t * 4 + 3) * 20;
        float q[6], p[6], a[6];
        #pragma unroll
        for (int e = 0; e < 6; ++e) {
            q[e] = r0[e] + r1[e] + r2[e] + r3[e];
            p[e] = r0[6 + e] + r1[6 + e] + r2[6 + e] + r3[6 + e];
            a[e] = r0[12 + e] + r1[12 + e] + r2[12 + e] + r3[12 + e];
        }
        float* dst = qp + ((size_t)(st * NB + bb) * NS + row0 + t) * 12;
        *(float4*)(dst + 0) = make_float4(q[0], q[1], q[2], q[3]);
        *(float4*)(dst + 4) = make_float4(q[4], q[5], p[0], p[1]);
        *(float4*)(dst + 8) = make_float4(p[2], p[3], p[4], p[5]);
        #pragma unroll
        for (int e = 0; e < 6; ++e) {
            float v = a[e];
            v += __shfl_xor(v, 1, 64);
            v += __shfl_xor(v, 2, 64);
            v += __shfl_xor(v, 4, 64);
            v += __shfl_xor(v, 8, 64);
            v += __shfl_xor(v, 16, 64);
            v += __shfl_xor(v, 32, 64);
            a[e] = v;
        }
        if (t == 0) {
            #pragma unroll
            for (int e = 0; e < 6; ++e) atomicAdd(&accsum[bb * NE + e], a[e]);
        }
    }
}

// ---------------- kernel D: per-batch global constant ----------------
__global__ __launch_bounds__(256) void k_const(
    const float* __restrict__ xt, const float* __restrict__ xa, const float* __restrict__ xv,
    const float* __restrict__ accsum, const float* __restrict__ A2F,
    const float* __restrict__ cb0, float* __restrict__ constb)
{
    const int b = blockIdx.x, t = threadIdx.x;
    const float* Xs[3] = { xt, xa, xv };
    float acc[NE] = {0, 0, 0, 0, 0, 0};
    for (int f = t; f < TD; f += 256) {
        const int st = f / DIM, dd = f - st * DIM;
        const float* Xp = Xs[st] + (size_t)b * NS * DIM;
        const float dm = Xp[(size_t)(NS - 1) * DIM + dd] - Xp[dd];
        const float* Ap = A2F + f * NE;
        #pragma unroll
        for (int e = 0; e < NE; ++e) acc[e] += dm * Ap[e];
    }
    #pragma unroll
    for (int e = 0; e < NE; ++e)
        for (int m = 1; m < 64; m <<= 1) acc[e] += __shfl_xor(acc[e], m, 64);
    __shared__ float wred[4][NE];
    if ((t & 63) == 0) {
        #pragma unroll
        for (int e = 0; e < NE; ++e) wred[t >> 6][e] = acc[e];
    }
    __syncthreads();
    if (t < NE) {
        const float inv = 1.f / 4096.f;
        const float dsum = wred[0][t] + wred[1][t] + wred[2][t] + wred[3][t];
        constb[b * NE + t] = cb0[t] + accsum[b * NE + t] * inv + dsum * inv;
    }
}

// ---------------- kernel E: combine q - shifted p + const ----------------
__global__ __launch_bounds__(256) void k_add(
    const float* __restrict__ qp, const float* __restrict__ constb, float* __restrict__ out)
{
    const int row = blockIdx.x * 256 + threadIdx.x;   // 32768 rows exact
    const int b = row >> 12, s = row & (NS - 1);
    const int rowp = (s == 0) ? row : row - 1;
    float o[NE];
    #pragma unroll
    for (int e = 0; e < NE; ++e) o[e] = constb[b * NE + e];
    #pragma unroll
    for (int st = 0; st < 3; ++st) {
        const float* qr = qp + ((size_t)st * NB * NS + row) * 12;
        const float* pr = qp + ((size_t)st * NB * NS + rowp) * 12;
        #pragma unroll
        for (int e = 0; e < NE; ++e) o[e] += qr[e] - pr[6 + e];
    }
    float* op = out + (size_t)row * NE;
    #pragma unroll
    for (int e = 0; e < NE; ++e) op[e] = o[e];
}

extern "C" void kernel_launch(void* const* d_in, const int* in_sizes, int n_in,
                              void* d_out, int out_size, void* d_ws, size_t ws_size,
                              hipStream_t stream)
{
    const float* xt     = (const float*)d_in[0];
    const float* xa     = (const float*)d_in[1];
    const float* xv     = (const float*)d_in[2];
    const float* Wspat  = (const float*)d_in[3];
    const float* bspat  = (const float*)d_in[4];
    const float* Wtemp  = (const float*)d_in[5];
    const float* btemp  = (const float*)d_in[6];
    const float* Wsync  = (const float*)d_in[7];
    const float* bsync  = (const float*)d_in[8];
    const float* Wglob  = (const float*)d_in[9];
    const float* bglob  = (const float*)d_in[10];
    const float* Wroute = (const float*)d_in[11];
    const float* broute = (const float*)d_in[12];
    float* out = (float*)d_out;

    float* ws     = (float*)d_ws;
    float* Qc3    = ws + OFF_QC3;
    float* A2F    = ws + OFF_A2F;
    float* cb0    = ws + OFF_CB0;
    float* accsum = ws + OFF_ACCSUM;
    float* constb = ws + OFF_CONSTB;
    float* qp     = ws + OFF_QP;

    k_fold<<<9, 256, 0, stream>>>(Wspat, Wtemp, Wsync, Wroute, Wglob, bglob,
                                  broute, bspat, btemp, bsync, Qc3, A2F, cb0, accsum);
    k_main<<<1536, 256, 0, stream>>>(xt, xa, xv, Qc3, accsum, qp);
    k_const<<<8, 256, 0, stream>>>(xt, xa, xv, accsum, A2F, cb0, constb);
    k_add<<<128, 256, 0, stream>>>(qp, constb, out);
}

// Round 10
// 160.775 us; speedup vs baseline: 7.8875x; 7.8875x over previous
//
#include <hip/hip_runtime.h>

#define DIM 768
#define TD 2304
#define NB 8
#define NS 4096
#define NE 6

// ws layout (float offsets)
#define OFF_QCAT   0        // [2304][12]: 0-5 Q, 6-11 P
#define OFF_A1F    27648    // [2304][6] colmean fold
#define OFF_A2F    41472    // [2304][6] delta-mean fold
#define OFF_CB0    55296    // [16]
#define OFF_CONSTB 55312    // [8][6] + pad = 64
#define OFF_COLSUM 55376    // [8][2304] = 18432
#define OFF_QP     73808    // [32768][12] = 393216

// ---------------- kernel B: fold all coefficient matrices (+cb0) ----------------
__global__ __launch_bounds__(256) void k_fold(
    const float* __restrict__ Wspat, const float* __restrict__ Wtemp,
    const float* __restrict__ Wsync, const float* __restrict__ Wroute,
    const float* __restrict__ Wglob, const float* __restrict__ bglob,
    const float* __restrict__ broute, const float* __restrict__ bspat,
    const float* __restrict__ btemp, const float* __restrict__ bsync,
    float* __restrict__ Qcat, float* __restrict__ A1F, float* __restrict__ A2F,
    float* __restrict__ cb0)
{
    __shared__ float lwr[288 * NE];
    __shared__ float lgf[224 * NE];
    const int t = threadIdx.x;
    for (int i = t; i < 288 * NE; i += 256) lwr[i] = Wroute[i];
    __syncthreads();
    if (t < 224) {
        float g[NE] = {0, 0, 0, 0, 0, 0};
        for (int o = 0; o < 64; ++o) {
            const float w = Wglob[t * 64 + o];
            #pragma unroll
            for (int e = 0; e < NE; ++e) g[e] += w * lwr[(224 + o) * NE + e];
        }
        #pragma unroll
        for (int e = 0; e < NE; ++e) lgf[t * NE + e] = g[e];
    }
    __syncthreads();
    if (blockIdx.x == 0 && t < NE) {
        float a = broute[t];
        for (int o = 0; o < 64; ++o)  a += bglob[o] * lwr[(224 + o) * NE + t];
        for (int o = 0; o < 128; ++o) a += bspat[o] * (lwr[o * NE + t] + lgf[o * NE + t]);
        for (int o = 0; o < 64; ++o)  a += btemp[o] * (lwr[(128 + o) * NE + t] + lgf[(128 + o) * NE + t]);
        for (int o = 0; o < 32; ++o)  a += bsync[o] * (lwr[(192 + o) * NE + t] + lgf[(192 + o) * NE + t]);
        cb0[t] = a;
    }

    const int d = blockIdx.x * 256 + t;          // exactly 2304 threads
    const int st = d / DIM, dd = d - st * DIM;

    float p[NE] = {0, 0, 0, 0, 0, 0}, a2[NE] = {0, 0, 0, 0, 0, 0};
    for (int o = 0; o < 64; ++o) {
        const float w = Wtemp[d * 64 + o];
        #pragma unroll
        for (int e = 0; e < NE; ++e) {
            p[e]  += w * lwr[(128 + o) * NE + e];
            a2[e] += w * lgf[(128 + o) * NE + e];
        }
    }
    float qq[NE], a1[NE];
    #pragma unroll
    for (int e = 0; e < NE; ++e) { qq[e] = p[e]; a1[e] = 0.f; }
    for (int o = 0; o < 128; ++o) {
        const float w = Wspat[d * 128 + o];
        #pragma unroll
        for (int e = 0; e < NE; ++e) {
            qq[e] += w * lwr[o * NE + e];
            a1[e] += w * lgf[o * NE + e];
        }
    }
    if (st != 0) {
        const float sg = (st == 1) ? 1.f : -1.f;
        for (int o = 0; o < 32; ++o) {
            const float w = sg * Wsync[dd * 32 + o];
            #pragma unroll
            for (int e = 0; e < NE; ++e) {
                qq[e] += w * lwr[(192 + o) * NE + e];
                a1[e] += w * lgf[(192 + o) * NE + e];
            }
        }
    }
    #pragma unroll
    for (int e = 0; e < NE; ++e) {
        Qcat[d * 12 + e]     = qq[e];
        Qcat[d * 12 + 6 + e] = p[e];
        A1F[d * NE + e] = a1[e];
        A2F[d * NE + e] = a2[e];
    }
}

// ---------------- kernel C: main streaming pass (r1 structure, 3-way col split) ----
// grid = 3split * (8b * 64rowblk) = 1536 blocks; 256 thr = 4 waves; block = 64 rows
// x 768 of the 2304 cols (per-quarter chunks [6s,6s+6)). Wave q owns quarter q.
// Lane = row for compute; scalar x reads (stride 33, conflict-free) + wave-uniform
// coefficient broadcasts from LDS. Register q/p accs -> LDS -> global atomicAdd.
__global__ __launch_bounds__(256, 2) void k_main(
    const float* __restrict__ xt, const float* __restrict__ xa, const float* __restrict__ xv,
    const float* __restrict__ Qcat, float* __restrict__ colsum, float* __restrict__ qp)
{
    __shared__ float sx[4 * 64 * 33];      // 33.8 KB
    __shared__ float scoef[4 * 32 * 12];   // 6 KB
    __shared__ float qacc[64 * NE];
    __shared__ float pacc[64 * NE];

    const int t = threadIdx.x;
    const int q = t >> 6;                  // quarter == wave
    const int l = t & 63;                  // lane == local row
    const int bid = blockIdx.x;
    const int s  = bid % 3;                // column split
    const int r2 = bid / 3;
    const int bb  = r2 >> 6;
    const int rb0 = (r2 & 63) << 6;
    const int j0 = s * 6;

    const float* Xs[3] = { xt, xa, xv };

    for (int i = t; i < 64 * NE; i += 256) { qacc[i] = 0.f; pacc[i] = 0.f; }

    const int c4  = l & 7;
    const int r0s = l >> 3;
    const int xrowbase = (bb * NS + rb0) * DIM;

    float4 hx[8];
    float4 hc0, hc1;

    auto issue_loads = [&](int jg) {
        const int D0 = q * 576 + jg * 32;          // chunks never straddle streams
        const int st = D0 / DIM, dd0 = D0 - st * DIM;
        const float* Xp = Xs[st] + xrowbase + dd0 + 4 * c4;
        #pragma unroll
        for (int k = 0; k < 8; ++k)
            hx[k] = *(const float4*)(Xp + (r0s + 8 * k) * DIM);
        {
            const int g = t, qg = g / 96, kk = g - qg * 96;
            hc0 = *(const float4*)(Qcat + ((qg * 576 + jg * 32) * 3 + kk) * 4);
        }
        if (t < 128) {
            const int g = 256 + t, qg = g / 96, kk = g - qg * 96;
            hc1 = *(const float4*)(Qcat + ((qg * 576 + jg * 32) * 3 + kk) * 4);
        }
    };

    auto write_stage = [&](int jg) {
        #pragma unroll
        for (int k = 0; k < 8; ++k) {              // scalar writes keep stride-33 layout
            float* dst = &sx[(q * 64 + r0s + 8 * k) * 33 + 4 * c4];
            dst[0] = hx[k].x; dst[1] = hx[k].y; dst[2] = hx[k].z; dst[3] = hx[k].w;
        }
        {
            const int g = t, qg = g / 96, kk = g - qg * 96;
            *(float4*)&scoef[qg * 384 + kk * 4] = hc0;
        }
        if (t < 128) {
            const int g = 256 + t, qg = g / 96, kk = g - qg * 96;
            *(float4*)&scoef[qg * 384 + kk * 4] = hc1;
        }
        // column-sum flush: lane's 8 rows, 4 fixed columns
        float cs0 = 0, cs1 = 0, cs2 = 0, cs3 = 0;
        #pragma unroll
        for (int k = 0; k < 8; ++k) { cs0 += hx[k].x; cs1 += hx[k].y; cs2 += hx[k].z; cs3 += hx[k].w; }
        #pragma unroll
        for (int m = 8; m < 64; m <<= 1) {
            cs0 += __shfl_xor(cs0, m, 64);
            cs1 += __shfl_xor(cs1, m, 64);
            cs2 += __shfl_xor(cs2, m, 64);
            cs3 += __shfl_xor(cs3, m, 64);
        }
        if (l < 8) {
            float* cp = &colsum[bb * TD + q * 576 + jg * 32 + 4 * l];
            atomicAdd(cp + 0, cs0);
            atomicAdd(cp + 1, cs1);
            atomicAdd(cp + 2, cs2);
            atomicAdd(cp + 3, cs3);
        }
    };

    issue_loads(j0);
    write_stage(j0);
    __syncthreads();

    float qv[NE] = {0, 0, 0, 0, 0, 0};
    float pv[NE] = {0, 0, 0, 0, 0, 0};

    for (int jj = 0; jj < 6; ++jj) {
        if (jj < 5) issue_loads(j0 + jj + 1);      // loads in flight during compute
        const float* xrow = &sx[(q * 64 + l) * 33];
        const float* cf   = &scoef[q * 384];
        #pragma unroll 8
        for (int c = 0; c < 32; ++c) {
            const float x = xrow[c];
            const float4 a  = *(const float4*)(cf + c * 12);
            const float4 b2 = *(const float4*)(cf + c * 12 + 4);
            const float4 c2 = *(const float4*)(cf + c * 12 + 8);
            qv[0] += x * a.x;  qv[1] += x * a.y;  qv[2] += x * a.z;  qv[3] += x * a.w;
            qv[4] += x * b2.x; qv[5] += x * b2.y;
            pv[0] += x * b2.z; pv[1] += x * b2.w;
            pv[2] += x * c2.x; pv[3] += x * c2.y; pv[4] += x * c2.z; pv[5] += x * c2.w;
        }
        __syncthreads();                            // everyone done reading tile
        if (jj < 5) { write_stage(j0 + jj + 1); __syncthreads(); }
    }

    #pragma unroll
    for (int e = 0; e < NE; ++e) atomicAdd(&qacc[l * NE + e], qv[e]);
    #pragma unroll
    for (int e = 0; e < NE; ++e) atomicAdd(&pacc[l * NE + e], pv[e]);
    __syncthreads();

    if (t < 64) {
        float* dst = qp + (size_t)(bb * NS + rb0 + t) * 12;
        #pragma unroll
        for (int e = 0; e < NE; ++e) {
            atomicAdd(dst + e, qacc[t * NE + e]);
            atomicAdd(dst + 6 + e, pacc[t * NE + e]);
        }
    }
}

// ---------------- kernel D: per-batch global constant ----------------
__global__ __launch_bounds__(256) void k_const(
    const float* __restrict__ xt, const float* __restrict__ xa, const float* __restrict__ xv,
    const float* __restrict__ colsum, const float* __restrict__ A1F,
    const float* __restrict__ A2F, const float* __restrict__ cb0,
    float* __restrict__ constb)
{
    const int b = blockIdx.x, t = threadIdx.x;
    const float* Xs[3] = { xt, xa, xv };
    float acc[NE] = {0, 0, 0, 0, 0, 0};
    for (int f = t; f < TD; f += 256) {
        const int st = f / DIM, dd = f - st * DIM;
        const float* Xp = Xs[st] + (size_t)b * NS * DIM;
        const float cs = colsum[b * TD + f];
        const float dm = Xp[(size_t)(NS - 1) * DIM + dd] - Xp[dd];
        const float* A1p = A1F + f * NE;
        const float* A2p = A2F + f * NE;
        #pragma unroll
        for (int e = 0; e < NE; ++e) acc[e] += cs * A1p[e] + dm * A2p[e];
    }
    #pragma unroll
    for (int e = 0; e < NE; ++e)
        for (int m = 1; m < 64; m <<= 1) acc[e] += __shfl_xor(acc[e], m, 64);
    __shared__ float wred[4][NE];
    if ((t & 63) == 0) {
        #pragma unroll
        for (int e = 0; e < NE; ++e) wred[t >> 6][e] = acc[e];
    }
    __syncthreads();
    if (t < NE) {
        const float inv = 1.f / 4096.f;
        constb[b * NE + t] = cb0[t] + (wred[0][t] + wred[1][t] + wred[2][t] + wred[3][t]) * inv;
    }
}

// ---------------- kernel E: combine q - shifted p + const ----------------
__global__ __launch_bounds__(256) void k_add(
    const float* __restrict__ qp, const float* __restrict__ constb, float* __restrict__ out)
{
    const int row = blockIdx.x * 256 + threadIdx.x;   // 32768 rows exact
    const int b = row >> 12, s = row & (NS - 1);
    const int rowp = (s == 0) ? row : row - 1;
    const float* qr = qp + (size_t)row * 12;
    const float* pr = qp + (size_t)rowp * 12;
    float* op = out + (size_t)row * NE;
    #pragma unroll
    for (int e = 0; e < NE; ++e)
        op[e] = constb[b * NE + e] + qr[e] - pr[6 + e];
}

extern "C" void kernel_launch(void* const* d_in, const int* in_sizes, int n_in,
                              void* d_out, int out_size, void* d_ws, size_t ws_size,
                              hipStream_t stream)
{
    const float* xt     = (const float*)d_in[0];
    const float* xa     = (const float*)d_in[1];
    const float* xv     = (const float*)d_in[2];
    const float* Wspat  = (const float*)d_in[3];
    const float* bspat  = (const float*)d_in[4];
    const float* Wtemp  = (const float*)d_in[5];
    const float* btemp  = (const float*)d_in[6];
    const float* Wsync  = (const float*)d_in[7];
    const float* bsync  = (const float*)d_in[8];
    const float* Wglob  = (const float*)d_in[9];
    const float* bglob  = (const float*)d_in[10];
    const float* Wroute = (const float*)d_in[11];
    const float* broute = (const float*)d_in[12];
    float* out = (float*)d_out;

    float* ws     = (float*)d_ws;
    float* Qcat   = ws + OFF_QCAT;
    float* A1F    = ws + OFF_A1F;
    float* A2F    = ws + OFF_A2F;
    float* cb0    = ws + OFF_CB0;
    float* constb = ws + OFF_CONSTB;
    float* colsum = ws + OFF_COLSUM;
    float* qp     = ws + OFF_QP;

    hipMemsetAsync(colsum, 0, (NB * TD) * sizeof(float), stream);
    hipMemsetAsync(qp, 0, (size_t)NB * NS * 12 * sizeof(float), stream);
    k_fold<<<9, 256, 0, stream>>>(Wspat, Wtemp, Wsync, Wroute, Wglob, bglob,
                                  broute, bspat, btemp, bsync, Qcat, A1F, A2F, cb0);
    k_main<<<1536, 256, 0, stream>>>(xt, xa, xv, Qcat, colsum, qp);
    k_const<<<8, 256, 0, stream>>>(xt, xa, xv, colsum, A1F, A2F, cb0, constb);
    k_add<<<128, 256, 0, stream>>>(qp, constb, out);
}

// Round 11
// 119.920 us; speedup vs baseline: 10.5746x; 1.3407x over previous
//
#include <hip/hip_runtime.h>

#define DIM 768
#define TD 2304
#define NB 8
#define NS 4096
#define NE 6

typedef __attribute__((ext_vector_type(8))) short bf16x8;
typedef __attribute__((ext_vector_type(4))) float f32x4;

// ws layout (float offsets)
#define OFF_BPK    0        // [72 ks][2 m][64 lane][8 j] u16 = 73728 u16 = 36864 f
#define OFF_A2F    36864    // [2304][6] f32 delta-mean fold
#define OFF_CB0    50688    // [16]
#define OFF_ACCSUM 50704    // [8][6] + pad = 64
#define OFF_CONSTB 50768    // [8][6] + pad = 64
#define OFF_QP2    50832    // [2 khalf][32768][12] = 786432

__device__ __forceinline__ unsigned short f2bf(float f) {
    union { float f; unsigned u; } a; a.f = f;
    unsigned r = a.u + 0x7FFFu + ((a.u >> 16) & 1u);
    return (unsigned short)(r >> 16);
}

// ---------------- kernel B: fold coefficients into MFMA B-fragment layout ----
__global__ __launch_bounds__(256) void k_fold(
    const float* __restrict__ Wspat, const float* __restrict__ Wtemp,
    const float* __restrict__ Wsync, const float* __restrict__ Wroute,
    const float* __restrict__ Wglob, const float* __restrict__ bglob,
    const float* __restrict__ broute, const float* __restrict__ bspat,
    const float* __restrict__ btemp, const float* __restrict__ bsync,
    unsigned short* __restrict__ Bpk, float* __restrict__ A2F,
    float* __restrict__ cb0, float* __restrict__ accsum)
{
    __shared__ float lwr[288 * NE];
    __shared__ float lgf[224 * NE];
    const int t = threadIdx.x;
    for (int i = t; i < 288 * NE; i += 256) lwr[i] = Wroute[i];
    __syncthreads();
    if (t < 224) {
        float g[NE] = {0, 0, 0, 0, 0, 0};
        for (int o = 0; o < 64; ++o) {
            const float w = Wglob[t * 64 + o];
            #pragma unroll
            for (int e = 0; e < NE; ++e) g[e] += w * lwr[(224 + o) * NE + e];
        }
        #pragma unroll
        for (int e = 0; e < NE; ++e) lgf[t * NE + e] = g[e];
    }
    __syncthreads();
    if (blockIdx.x == 0) {
        if (t < NE) {
            float a = broute[t];
            for (int o = 0; o < 64; ++o)  a += bglob[o] * lwr[(224 + o) * NE + t];
            for (int o = 0; o < 128; ++o) a += bspat[o] * (lwr[o * NE + t] + lgf[o * NE + t]);
            for (int o = 0; o < 64; ++o)  a += btemp[o] * (lwr[(128 + o) * NE + t] + lgf[(128 + o) * NE + t]);
            for (int o = 0; o < 32; ++o)  a += bsync[o] * (lwr[(192 + o) * NE + t] + lgf[(192 + o) * NE + t]);
            cb0[t] = a;
        }
        if (t >= 128 && t < 192) accsum[t - 128] = 0.f;
    }

    const int d = blockIdx.x * 256 + t;          // exactly 2304 threads
    const int st = d / DIM, dd = d - st * DIM;

    float p[NE] = {0, 0, 0, 0, 0, 0}, a2[NE] = {0, 0, 0, 0, 0, 0};
    for (int o = 0; o < 64; ++o) {
        const float w = Wtemp[d * 64 + o];
        #pragma unroll
        for (int e = 0; e < NE; ++e) {
            p[e]  += w * lwr[(128 + o) * NE + e];
            a2[e] += w * lgf[(128 + o) * NE + e];
        }
    }
    float qq[NE], a1[NE];
    #pragma unroll
    for (int e = 0; e < NE; ++e) { qq[e] = p[e]; a1[e] = 0.f; }
    for (int o = 0; o < 128; ++o) {
        const float w = Wspat[d * 128 + o];
        #pragma unroll
        for (int e = 0; e < NE; ++e) {
            qq[e] += w * lwr[o * NE + e];
            a1[e] += w * lgf[o * NE + e];
        }
    }
    if (st != 0) {
        const float sg = (st == 1) ? 1.f : -1.f;
        for (int o = 0; o < 32; ++o) {
            const float w = sg * Wsync[dd * 32 + o];
            #pragma unroll
            for (int e = 0; e < NE; ++e) {
                qq[e] += w * lwr[(192 + o) * NE + e];
                a1[e] += w * lgf[(192 + o) * NE + e];
            }
        }
    }
    // B-fragment scatter: B[k][n], k=d. frag: lane = (kk>>3)*16 + n, j = kk&7.
    const int ks = d >> 5, kk = d & 31;
    const int lh = (kk >> 3) * 16, j = kk & 7;
    unsigned short* b0 = Bpk + ks * 1024 + j;          // m=0 (Q/P outs 0-11)
    unsigned short* b1 = b0 + 512;                     // m=1 (A1 outs 0-5)
    #pragma unroll
    for (int e = 0; e < NE; ++e) {
        b0[(lh + e) * 8]     = f2bf(qq[e]);
        b0[(lh + 6 + e) * 8] = f2bf(p[e]);
        b1[(lh + e) * 8]     = f2bf(a1[e]);
        A2F[d * NE + e] = a2[e];
    }
}

// ---------------- kernel C: MFMA streaming GEMM ----------------
// grid = 512 row-blocks * 2 k-halves = 1024; 256 thr = 4 waves; block = 64 rows
// x 1152 cols. Wave w owns rows w*16..w*16+15 (one 16x16x32 MFMA row-group).
// Per 64-col chunk: stage x (f32->bf16, frag layout) to LDS double-buffered;
// compute = 2 ds_read_b128 (A) + 4 global b128 (B, L2-hot) + 4 MFMA. The dot
// products run on the matrix pipe — VALU and DS pipes stay nearly idle.

#define GLOAD(C) { \
    const int gc0 = (khalf * 18 + (C)) * 64; \
    const int st_ = gc0 / DIM; \
    const float* Xp_ = (st_ == 0) ? xt : ((st_ == 1) ? xa : xv); \
    const float* Xr = Xp_ + (size_t)(rb0 + rloc) * DIM + (gc0 - st_ * DIM) + o * 8; \
    g0 = *(const float4*)(Xr);       g1 = *(const float4*)(Xr + 4); \
    g2 = *(const float4*)(Xr + DIM); g3 = *(const float4*)(Xr + DIM + 4); }

#define BLOAD(C, B00, B01, B10, B11) { \
    const unsigned short* bp = Bpk + ((khalf * 18 + (C)) << 11) + (l << 3); \
    B00 = *(const bf16x8*)(bp); \
    B01 = *(const bf16x8*)(bp + 512); \
    B10 = *(const bf16x8*)(bp + 1024); \
    B11 = *(const bf16x8*)(bp + 1536); }

#define STAGE(DB) { \
    bf16x8 v0, v1; \
    v0[0] = (short)f2bf(g0.x); v0[1] = (short)f2bf(g0.y); \
    v0[2] = (short)f2bf(g0.z); v0[3] = (short)f2bf(g0.w); \
    v0[4] = (short)f2bf(g1.x); v0[5] = (short)f2bf(g1.y); \
    v0[6] = (short)f2bf(g1.z); v0[7] = (short)f2bf(g1.w); \
    v1[0] = (short)f2bf(g2.x); v1[1] = (short)f2bf(g2.y); \
    v1[2] = (short)f2bf(g2.z); v1[3] = (short)f2bf(g2.w); \
    v1[4] = (short)f2bf(g3.x); v1[5] = (short)f2bf(g3.y); \
    v1[6] = (short)f2bf(g3.z); v1[7] = (short)f2bf(g3.w); \
    *(bf16x8*)&abuf[(DB) * 4096 + woff]     = v0; \
    *(bf16x8*)&abuf[(DB) * 4096 + woff + 8] = v1; }

#define COMPUTE(DB) { \
    const bf16x8 A0 = *(const bf16x8*)&abuf[(DB) * 4096 + (w * 512) + (l << 3)]; \
    const bf16x8 A1 = *(const bf16x8*)&abuf[(DB) * 4096 + 2048 + (w * 512) + (l << 3)]; \
    acc0 = __builtin_amdgcn_mfma_f32_16x16x32_bf16(A0, Bc00, acc0, 0, 0, 0); \
    acc1 = __builtin_amdgcn_mfma_f32_16x16x32_bf16(A0, Bc01, acc1, 0, 0, 0); \
    acc0 = __builtin_amdgcn_mfma_f32_16x16x32_bf16(A1, Bc10, acc0, 0, 0, 0); \
    acc1 = __builtin_amdgcn_mfma_f32_16x16x32_bf16(A1, Bc11, acc1, 0, 0, 0); }

__global__ __launch_bounds__(256, 4) void k_main(
    const float* __restrict__ xt, const float* __restrict__ xa, const float* __restrict__ xv,
    const unsigned short* __restrict__ Bpk, float* __restrict__ accsum,
    float* __restrict__ qp2)
{
    __shared__ unsigned short abuf[2 * 8 * 512];   // 16 KB: [db][ks*4+wg][lane][8]
    const int t = threadIdx.x;
    const int l = t & 63;
    const int w = t >> 6;
    const int bid = blockIdx.x;
    const int khalf = bid & 1;
    const int rblk = bid >> 1;
    const int rb0 = rblk << 6;
    const int bb = rblk >> 6;

    // staging map: thread t stages rows rloc, rloc+1, cols o*8..o*8+7 of chunk
    const int o = t & 7;
    const int rloc = (t >> 3) * 2;
    const int woff = (((o >> 2) * 4 + (rloc >> 4)) * 64 + (o & 3) * 16 + (rloc & 15)) * 8;

    f32x4 acc0 = {0.f, 0.f, 0.f, 0.f};
    f32x4 acc1 = {0.f, 0.f, 0.f, 0.f};
    float4 g0, g1, g2, g3;
    bf16x8 Bc00, Bc01, Bc10, Bc11, Bn00, Bn01, Bn10, Bn11;

    GLOAD(0)
    BLOAD(0, Bc00, Bc01, Bc10, Bc11)
    STAGE(0)
    __syncthreads();

    int db = 0;
    #pragma unroll 1
    for (int c = 0; c < 18; ++c) {
        if (c < 17) { GLOAD(c + 1) BLOAD(c + 1, Bn00, Bn01, Bn10, Bn11) }
        COMPUTE(db)
        __syncthreads();
        if (c < 17) {
            STAGE(db ^ 1)
            Bc00 = Bn00; Bc01 = Bn01; Bc10 = Bn10; Bc11 = Bn11;
            __syncthreads();
            db ^= 1;
        }
    }

    // epilogue: D layout col=lane&15, row=(lane>>4)*4+reg
    const int c_out = l & 15, rgrp = l >> 4;
    float* qph = qp2 + (size_t)khalf * ((size_t)NB * NS * 12);
    if (c_out < 12) {
        const size_t rbase = (size_t)(rb0 + w * 16 + rgrp * 4) * 12 + c_out;
        qph[rbase]      = acc0[0];
        qph[rbase + 12] = acc0[1];
        qph[rbase + 24] = acc0[2];
        qph[rbase + 36] = acc0[3];
    }
    float v = acc1[0] + acc1[1] + acc1[2] + acc1[3];
    v += __shfl_xor(v, 16, 64);
    v += __shfl_xor(v, 32, 64);
    if (rgrp == 0 && c_out < 6)
        atomicAdd(&accsum[bb * NE + c_out], v);
}

// ---------------- kernel D: per-batch global constant ----------------
__global__ __launch_bounds__(256) void k_const(
    const float* __restrict__ xt, const float* __restrict__ xa, const float* __restrict__ xv,
    const float* __restrict__ accsum, const float* __restrict__ A2F,
    const float* __restrict__ cb0, float* __restrict__ constb)
{
    const int b = blockIdx.x, t = threadIdx.x;
    float acc[NE] = {0, 0, 0, 0, 0, 0};
    for (int f = t; f < TD; f += 256) {
        const int st = f / DIM, dd = f - st * DIM;
        const float* Xp = ((st == 0) ? xt : ((st == 1) ? xa : xv)) + (size_t)b * NS * DIM;
        const float dm = Xp[(size_t)(NS - 1) * DIM + dd] - Xp[dd];
        const float* Ap = A2F + f * NE;
        #pragma unroll
        for (int e = 0; e < NE; ++e) acc[e] += dm * Ap[e];
    }
    #pragma unroll
    for (int e = 0; e < NE; ++e)
        for (int m = 1; m < 64; m <<= 1) acc[e] += __shfl_xor(acc[e], m, 64);
    __shared__ float wred[4][NE];
    if ((t & 63) == 0) {
        #pragma unroll
        for (int e = 0; e < NE; ++e) wred[t >> 6][e] = acc[e];
    }
    __syncthreads();
    if (t < NE) {
        const float inv = 1.f / 4096.f;
        const float dsum = wred[0][t] + wred[1][t] + wred[2][t] + wred[3][t];
        constb[b * NE + t] = cb0[t] + accsum[b * NE + t] * inv + dsum * inv;
    }
}

// ---------------- kernel E: combine q - shifted p + const ----------------
__global__ __launch_bounds__(256) void k_add(
    const float* __restrict__ qp2, const float* __restrict__ constb, float* __restrict__ out)
{
    const int row = blockIdx.x * 256 + threadIdx.x;   // 32768 rows exact
    const int b = row >> 12, s = row & (NS - 1);
    const int rowp = (s == 0) ? row : row - 1;
    const size_t H = (size_t)NB * NS * 12;
    const float* q0 = qp2 + (size_t)row * 12;
    const float* q1 = qp2 + H + (size_t)row * 12;
    const float* p0 = qp2 + (size_t)rowp * 12 + 6;
    const float* p1 = qp2 + H + (size_t)rowp * 12 + 6;
    float* op = out + (size_t)row * NE;
    #pragma unroll
    for (int e = 0; e < NE; ++e)
        op[e] = constb[b * NE + e] + q0[e] + q1[e] - p0[e] - p1[e];
}

extern "C" void kernel_launch(void* const* d_in, const int* in_sizes, int n_in,
                              void* d_out, int out_size, void* d_ws, size_t ws_size,
                              hipStream_t stream)
{
    const float* xt     = (const float*)d_in[0];
    const float* xa     = (const float*)d_in[1];
    const float* xv     = (const float*)d_in[2];
    const float* Wspat  = (const float*)d_in[3];
    const float* bspat  = (const float*)d_in[4];
    const float* Wtemp  = (const float*)d_in[5];
    const float* btemp  = (const float*)d_in[6];
    const float* Wsync  = (const float*)d_in[7];
    const float* bsync  = (const float*)d_in[8];
    const float* Wglob  = (const float*)d_in[9];
    const float* bglob  = (const float*)d_in[10];
    const float* Wroute = (const float*)d_in[11];
    const float* broute = (const float*)d_in[12];
    float* out = (float*)d_out;

    float* ws = (float*)d_ws;
    unsigned short* Bpk = (unsigned short*)(ws + OFF_BPK);
    float* A2F    = ws + OFF_A2F;
    float* cb0    = ws + OFF_CB0;
    float* accsum = ws + OFF_ACCSUM;
    float* constb = ws + OFF_CONSTB;
    float* qp2    = ws + OFF_QP2;

    hipMemsetAsync(Bpk, 0, 73728 * sizeof(unsigned short), stream);
    k_fold<<<9, 256, 0, stream>>>(Wspat, Wtemp, Wsync, Wroute, Wglob, bglob,
                                  broute, bspat, btemp, bsync, Bpk, A2F, cb0, accsum);
    k_main<<<1024, 256, 0, stream>>>(xt, xa, xv, Bpk, accsum, qp2);
    k_const<<<8, 256, 0, stream>>>(xt, xa, xv, accsum, A2F, cb0, constb);
    k_add<<<128, 256, 0, stream>>>(qp2, constb, out);
}

// Round 12
// 114.637 us; speedup vs baseline: 11.0619x; 1.0461x over previous
//
#include <hip/hip_runtime.h>
#include <hip/hip_bf16.h>

#define DIM 768
#define TD 2304
#define NB 8
#define NS 4096
#define NE 6

typedef __attribute__((ext_vector_type(8))) short bf16x8;
typedef __attribute__((ext_vector_type(4))) float f32x4;

// ws layout (float offsets)
#define OFF_BPK    0        // [72 ks][2 m][64 lane][8 j] u16 = 73728 u16 = 36864 f
#define OFF_A2F    36864    // [2304][6] f32 delta-mean fold
#define OFF_CB0    50688    // [16]
#define OFF_ACCSUM 50704    // [8][6] + pad = 64
#define OFF_CONSTB 50768    // [8][6] + pad = 64
#define OFF_QP2    50832    // [2 khalf][32768][12] = 786432

__device__ __forceinline__ unsigned short f2bf(float f) {
    union { float f; unsigned u; } a; a.f = f;
    unsigned r = a.u + 0x7FFFu + ((a.u >> 16) & 1u);
    return (unsigned short)(r >> 16);
}

__device__ __forceinline__ bf16x8 pack8(float4 a, float4 b) {
    union { bf16x8 v; __hip_bfloat162 h[4]; } u;
    u.h[0] = __float22bfloat162_rn(make_float2(a.x, a.y));
    u.h[1] = __float22bfloat162_rn(make_float2(a.z, a.w));
    u.h[2] = __float22bfloat162_rn(make_float2(b.x, b.y));
    u.h[3] = __float22bfloat162_rn(make_float2(b.z, b.w));
    return u.v;
}

// ---------------- kernel B: fold coefficients into MFMA B-fragment layout ----
__global__ __launch_bounds__(256) void k_fold(
    const float* __restrict__ Wspat, const float* __restrict__ Wtemp,
    const float* __restrict__ Wsync, const float* __restrict__ Wroute,
    const float* __restrict__ Wglob, const float* __restrict__ bglob,
    const float* __restrict__ broute, const float* __restrict__ bspat,
    const float* __restrict__ btemp, const float* __restrict__ bsync,
    unsigned short* __restrict__ Bpk, float* __restrict__ A2F,
    float* __restrict__ cb0, float* __restrict__ accsum)
{
    __shared__ float lwr[288 * NE];
    __shared__ float lgf[224 * NE];
    const int t = threadIdx.x;
    for (int i = t; i < 288 * NE; i += 256) lwr[i] = Wroute[i];
    __syncthreads();
    if (t < 224) {
        float g[NE] = {0, 0, 0, 0, 0, 0};
        for (int o = 0; o < 64; ++o) {
            const float w = Wglob[t * 64 + o];
            #pragma unroll
            for (int e = 0; e < NE; ++e) g[e] += w * lwr[(224 + o) * NE + e];
        }
        #pragma unroll
        for (int e = 0; e < NE; ++e) lgf[t * NE + e] = g[e];
    }
    __syncthreads();
    if (blockIdx.x == 0) {
        if (t < NE) {
            float a = broute[t];
            for (int o = 0; o < 64; ++o)  a += bglob[o] * lwr[(224 + o) * NE + t];
            for (int o = 0; o < 128; ++o) a += bspat[o] * (lwr[o * NE + t] + lgf[o * NE + t]);
            for (int o = 0; o < 64; ++o)  a += btemp[o] * (lwr[(128 + o) * NE + t] + lgf[(128 + o) * NE + t]);
            for (int o = 0; o < 32; ++o)  a += bsync[o] * (lwr[(192 + o) * NE + t] + lgf[(192 + o) * NE + t]);
            cb0[t] = a;
        }
        if (t >= 128 && t < 192) accsum[t - 128] = 0.f;
    }

    const int d = blockIdx.x * 256 + t;          // exactly 2304 threads
    const int st = d / DIM, dd = d - st * DIM;

    float p[NE] = {0, 0, 0, 0, 0, 0}, a2[NE] = {0, 0, 0, 0, 0, 0};
    for (int o = 0; o < 64; ++o) {
        const float w = Wtemp[d * 64 + o];
        #pragma unroll
        for (int e = 0; e < NE; ++e) {
            p[e]  += w * lwr[(128 + o) * NE + e];
            a2[e] += w * lgf[(128 + o) * NE + e];
        }
    }
    float qq[NE], a1[NE];
    #pragma unroll
    for (int e = 0; e < NE; ++e) { qq[e] = p[e]; a1[e] = 0.f; }
    for (int o = 0; o < 128; ++o) {
        const float w = Wspat[d * 128 + o];
        #pragma unroll
        for (int e = 0; e < NE; ++e) {
            qq[e] += w * lwr[o * NE + e];
            a1[e] += w * lgf[o * NE + e];
        }
    }
    if (st != 0) {
        const float sg = (st == 1) ? 1.f : -1.f;
        for (int o = 0; o < 32; ++o) {
            const float w = sg * Wsync[dd * 32 + o];
            #pragma unroll
            for (int e = 0; e < NE; ++e) {
                qq[e] += w * lwr[(192 + o) * NE + e];
                a1[e] += w * lgf[(192 + o) * NE + e];
            }
        }
    }
    // B-fragment scatter: B[k][n], k=d. frag: lane = (kk>>3)*16 + n, j = kk&7.
    const int ks = d >> 5, kk = d & 31;
    const int lh = (kk >> 3) * 16, j = kk & 7;
    unsigned short* b0 = Bpk + ks * 1024 + j;          // m=0 (Q/P outs 0-11)
    unsigned short* b1 = b0 + 512;                     // m=1 (A1 outs 0-5)
    #pragma unroll
    for (int e = 0; e < NE; ++e) {
        b0[(lh + e) * 8]     = f2bf(qq[e]);
        b0[(lh + 6 + e) * 8] = f2bf(p[e]);
        b1[(lh + e) * 8]     = f2bf(a1[e]);
        A2F[d * NE + e] = a2[e];
    }
}

// ---------------- kernel C: MFMA streaming GEMM, no LDS, no barriers ----------------
// grid = 512 row-blocks * 2 k-halves = 1024; 256 thr = 4 independent waves.
// Wave w owns rows rb0+w*16..+15 and K-range khalf*1152..+1151 (18 chunks of 64).
// A-fragments loaded DIRECTLY from global: lane l -> row (l&15), k-slice
// (l>>4)*8, 8 contiguous f32 = 2 float4. Convert via v_cvt_pk (pack8), 4 MFMA
// per chunk. Register ping-pong depth 2; zero LDS, zero __syncthreads.

#define GLOADX(A0, A1, A2, A3, C) { \
    const int gc_ = khalf * 1152 + (C) * 64; \
    const int st_ = gc_ / DIM; \
    const float* Xp_ = (st_ == 0) ? xt : ((st_ == 1) ? xa : xv); \
    const float* Xr_ = Xp_ + rowoff + (gc_ - st_ * DIM); \
    A0 = *(const float4*)(Xr_);      A1 = *(const float4*)(Xr_ + 4); \
    A2 = *(const float4*)(Xr_ + 32); A3 = *(const float4*)(Xr_ + 36); }

#define BLOAD(C, B00, B01, B10, B11) { \
    const unsigned short* bp = Bpk + ((khalf * 18 + (C)) << 11) + (l << 3); \
    B00 = *(const bf16x8*)(bp); \
    B01 = *(const bf16x8*)(bp + 512); \
    B10 = *(const bf16x8*)(bp + 1024); \
    B11 = *(const bf16x8*)(bp + 1536); }

#define CMPT(A0, A1, A2, A3, B00, B01, B10, B11) { \
    const bf16x8 fA0 = pack8(A0, A1); \
    const bf16x8 fA1 = pack8(A2, A3); \
    acc0 = __builtin_amdgcn_mfma_f32_16x16x32_bf16(fA0, B00, acc0, 0, 0, 0); \
    acc1 = __builtin_amdgcn_mfma_f32_16x16x32_bf16(fA0, B01, acc1, 0, 0, 0); \
    acc0 = __builtin_amdgcn_mfma_f32_16x16x32_bf16(fA1, B10, acc0, 0, 0, 0); \
    acc1 = __builtin_amdgcn_mfma_f32_16x16x32_bf16(fA1, B11, acc1, 0, 0, 0); }

__global__ __launch_bounds__(256, 4) void k_main(
    const float* __restrict__ xt, const float* __restrict__ xa, const float* __restrict__ xv,
    const unsigned short* __restrict__ Bpk, float* __restrict__ accsum,
    float* __restrict__ qp2)
{
    const int t = threadIdx.x;
    const int l = t & 63;
    const int w = t >> 6;
    const int bid = blockIdx.x;
    const int khalf = bid & 1;
    const int rblk = bid >> 1;
    const int rb0 = rblk << 6;
    const int bb = rblk >> 6;

    const int arow = rb0 + w * 16 + (l & 15);
    const size_t rowoff = (size_t)arow * DIM + (l >> 4) * 8;

    f32x4 acc0 = {0.f, 0.f, 0.f, 0.f};
    f32x4 acc1 = {0.f, 0.f, 0.f, 0.f};

    float4 pa0, pa1, pa2, pa3, pb0, pb1, pb2, pb3;
    bf16x8 Ba00, Ba01, Ba10, Ba11, Bb00, Bb01, Bb10, Bb11;

    GLOADX(pa0, pa1, pa2, pa3, 0)
    BLOAD(0, Ba00, Ba01, Ba10, Ba11)
    GLOADX(pb0, pb1, pb2, pb3, 1)
    BLOAD(1, Bb00, Bb01, Bb10, Bb11)

    #pragma unroll 1
    for (int c = 0; c < 16; c += 2) {
        CMPT(pa0, pa1, pa2, pa3, Ba00, Ba01, Ba10, Ba11)
        GLOADX(pa0, pa1, pa2, pa3, c + 2)
        BLOAD(c + 2, Ba00, Ba01, Ba10, Ba11)
        CMPT(pb0, pb1, pb2, pb3, Bb00, Bb01, Bb10, Bb11)
        GLOADX(pb0, pb1, pb2, pb3, c + 3)
        BLOAD(c + 3, Bb00, Bb01, Bb10, Bb11)
    }
    CMPT(pa0, pa1, pa2, pa3, Ba00, Ba01, Ba10, Ba11)
    CMPT(pb0, pb1, pb2, pb3, Bb00, Bb01, Bb10, Bb11)

    // epilogue: D layout col=lane&15, row=(lane>>4)*4+reg
    const int c_out = l & 15, rgrp = l >> 4;
    float* qph = qp2 + (size_t)khalf * ((size_t)NB * NS * 12);
    if (c_out < 12) {
        const size_t rbase = (size_t)(rb0 + w * 16 + rgrp * 4) * 12 + c_out;
        qph[rbase]      = acc0[0];
        qph[rbase + 12] = acc0[1];
        qph[rbase + 24] = acc0[2];
        qph[rbase + 36] = acc0[3];
    }
    float v = acc1[0] + acc1[1] + acc1[2] + acc1[3];
    v += __shfl_xor(v, 16, 64);
    v += __shfl_xor(v, 32, 64);
    if (rgrp == 0 && c_out < 6)
        atomicAdd(&accsum[bb * NE + c_out], v);
}

// ---------------- kernel D: per-batch global constant ----------------
__global__ __launch_bounds__(256) void k_const(
    const float* __restrict__ xt, const float* __restrict__ xa, const float* __restrict__ xv,
    const float* __restrict__ accsum, const float* __restrict__ A2F,
    const float* __restrict__ cb0, float* __restrict__ constb)
{
    const int b = blockIdx.x, t = threadIdx.x;
    float acc[NE] = {0, 0, 0, 0, 0, 0};
    for (int f = t; f < TD; f += 256) {
        const int st = f / DIM, dd = f - st * DIM;
        const float* Xp = ((st == 0) ? xt : ((st == 1) ? xa : xv)) + (size_t)b * NS * DIM;
        const float dm = Xp[(size_t)(NS - 1) * DIM + dd] - Xp[dd];
        const float* Ap = A2F + f * NE;
        #pragma unroll
        for (int e = 0; e < NE; ++e) acc[e] += dm * Ap[e];
    }
    #pragma unroll
    for (int e = 0; e < NE; ++e)
        for (int m = 1; m < 64; m <<= 1) acc[e] += __shfl_xor(acc[e], m, 64);
    __shared__ float wred[4][NE];
    if ((t & 63) == 0) {
        #pragma unroll
        for (int e = 0; e < NE; ++e) wred[t >> 6][e] = acc[e];
    }
    __syncthreads();
    if (t < NE) {
        const float inv = 1.f / 4096.f;
        const float dsum = wred[0][t] + wred[1][t] + wred[2][t] + wred[3][t];
        constb[b * NE + t] = cb0[t] + accsum[b * NE + t] * inv + dsum * inv;
    }
}

// ---------------- kernel E: combine q - shifted p + const ----------------
__global__ __launch_bounds__(256) void k_add(
    const float* __restrict__ qp2, const float* __restrict__ constb, float* __restrict__ out)
{
    const int row = blockIdx.x * 256 + threadIdx.x;   // 32768 rows exact
    const int b = row >> 12, s = row & (NS - 1);
    const int rowp = (s == 0) ? row : row - 1;
    const size_t H = (size_t)NB * NS * 12;
    const float* q0 = qp2 + (size_t)row * 12;
    const float* q1 = qp2 + H + (size_t)row * 12;
    const float* p0 = qp2 + (size_t)rowp * 12 + 6;
    const float* p1 = qp2 + H + (size_t)rowp * 12 + 6;
    float* op = out + (size_t)row * NE;
    #pragma unroll
    for (int e = 0; e < NE; ++e)
        op[e] = constb[b * NE + e] + q0[e] + q1[e] - p0[e] - p1[e];
}

extern "C" void kernel_launch(void* const* d_in, const int* in_sizes, int n_in,
                              void* d_out, int out_size, void* d_ws, size_t ws_size,
                              hipStream_t stream)
{
    const float* xt     = (const float*)d_in[0];
    const float* xa     = (const float*)d_in[1];
    const float* xv     = (const float*)d_in[2];
    const float* Wspat  = (const float*)d_in[3];
    const float* bspat  = (const float*)d_in[4];
    const float* Wtemp  = (const float*)d_in[5];
    const float* btemp  = (const float*)d_in[6];
    const float* Wsync  = (const float*)d_in[7];
    const float* bsync  = (const float*)d_in[8];
    const float* Wglob  = (const float*)d_in[9];
    const float* bglob  = (const float*)d_in[10];
    const float* Wroute = (const float*)d_in[11];
    const float* broute = (const float*)d_in[12];
    float* out = (float*)d_out;

    float* ws = (float*)d_ws;
    unsigned short* Bpk = (unsigned short*)(ws + OFF_BPK);
    float* A2F    = ws + OFF_A2F;
    float* cb0    = ws + OFF_CB0;
    float* accsum = ws + OFF_ACCSUM;
    float* constb = ws + OFF_CONSTB;
    float* qp2    = ws + OFF_QP2;

    hipMemsetAsync(Bpk, 0, 73728 * sizeof(unsigned short), stream);
    k_fold<<<9, 256, 0, stream>>>(Wspat, Wtemp, Wsync, Wroute, Wglob, bglob,
                                  broute, bspat, btemp, bsync, Bpk, A2F, cb0, accsum);
    k_main<<<1024, 256, 0, stream>>>(xt, xa, xv, Bpk, accsum, qp2);
    k_const<<<8, 256, 0, stream>>>(xt, xa, xv, accsum, A2F, cb0, constb);
    k_add<<<128, 256, 0, stream>>>(qp2, constb, out);
}